// Round 5
// baseline (441.243 us; speedup 1.0000x reference)
//
#include <hip/hip_runtime.h>

// ConvMlp4d: conv4d(64->128) + bias + relu -> conv4d(128->64) + bias.
// R15: pinned software pipeline + double-width wave tile.
//   Key finding (R14 VGPR=96): the compiler SINKS all B/A loads to just
//   before their MFMA cluster (live-range shrink), destroying every
//   source-level prefetch tried in R10-R14 -> ~40% MfmaUtil invariant.
//   Fixes:
//   - sched_barrier(0) fences between every {load bundle} and {MFMA
//     cluster}: loads stay 1+ cluster (768 cyc) ahead of use.
//   - wave tile M=128 x N=64 (acc[4][2] f32x16 = 128 VGPR): 24-MFMA
//     clusters, A-traffic/MFMA halved to 256B, per-iter overhead halved.
//   - block = 2 waves M-stacked: M=256 (VSPAN=8, ROWS=10), N=64.
//     Both waves load IDENTICAL B addresses (L1-dedup). LDS 45KB, 3/CU.
//   - DMA(i+1) issued after ALL B loads of iter i (younger -> B-consumer
//     waits never force-drain it); raw s_barrier + own-wave vmcnt(0) at top.
//   - t bits at bid[8:9]: co-resident blocks get different t -> the
//     18..36-stage U imbalance averages per CU.
//   conv1: <64,128,NSPLIT=2> grid 1024; conv2: <128,64,1> grid 512.
//   ws: x_t bf16 [2][65536][64] | h_t bf16 [2][65536][128] (chunk-planar:
//       [nb][tu][v][chunk=c/8][w][c%8])
//       w1t bf16 [81][4][128][16] | w2t bf16 [81][8][64][16] | zpage 4KB

using bf16x8 = __attribute__((ext_vector_type(8))) __bf16;
using f32x16 = __attribute__((ext_vector_type(16))) float;
using f32x4  = __attribute__((ext_vector_type(4))) float;

typedef __attribute__((address_space(1))) const void as1_void;
typedef __attribute__((address_space(3))) void as3_void;
__device__ __forceinline__ void gload_lds16(const void* g, void* l) {
    __builtin_amdgcn_global_load_lds((as1_void*)g, (as3_void*)l, 16, 0, 0);
}
#define SBAR() __builtin_amdgcn_sched_barrier(0)

// ------- prep: x (2,64,65536) f32 -> x_t chunk-planar bf16; zero the zpage --------
__global__ __launch_bounds__(256) void cvt_x(const float* __restrict__ x,
                                             __bf16* __restrict__ x_t,
                                             __bf16* __restrict__ zp) {
    __shared__ float lt[64][65];
    if (blockIdx.x == 0 && blockIdx.y == 0)
        *(uint4*)((char*)zp + threadIdx.x * 16) = make_uint4(0u, 0u, 0u, 0u);
    const int nb = blockIdx.y;
    const int p0 = blockIdx.x * 64;
    const int tu = p0 >> 10;
    const float* src = x + (size_t)nb * 64 * 65536;
    __bf16* dst = x_t + (size_t)nb * 65536 * 64;
    #pragma unroll
    for (int i = 0; i < 16; ++i) {
        int idx = i * 256 + threadIdx.x;
        int c = idx >> 6, p = idx & 63;
        lt[c][p] = src[(size_t)c * 65536 + p0 + p];
    }
    __syncthreads();
    #pragma unroll
    for (int it = 0; it < 2; ++it) {
        int idx = it * 256 + threadIdx.x;
        int pl = idx & 63;
        int chunk = idx >> 6;
        int p = p0 + pl;
        int v = (p >> 5) & 31, w = p & 31;
        bf16x8 pk;
        #pragma unroll
        for (int e = 0; e < 8; ++e)
            pk[e] = (__bf16)lt[chunk * 8 + e][pl];
        *(bf16x8*)(dst + (size_t)(tu * 32 + v) * 2048 + chunk * 256 + w * 8) = pk;
    }
}

// ------- prep: w (O,CIN,81) f32 -> wt [81][CIN/16][COUT][16] bf16 ------------------
template <int CIN>
__global__ __launch_bounds__(256) void cvt_w(const float* __restrict__ w,
                                             __bf16* __restrict__ wt) {
    constexpr int COUT = 8192 / CIN;
    constexpr int LOGC = (CIN == 64) ? 7 : 6;   // log2(COUT)
    const int tap = blockIdx.x;                 // 0..80
    __bf16* dst = wt + (size_t)tap * 8192;
    #pragma unroll
    for (int it = 0; it < 32; ++it) {
        const int i  = it * 256 + threadIdx.x;  // kg*(COUT*16) + o*16 + cl
        const int cl = i & 15;
        const int o  = (i >> 4) & (COUT - 1);
        const int kg = i >> (4 + LOGC);
        dst[i] = (__bf16)w[(size_t)(o * CIN + kg * 16 + cl) * 81 + tap];
    }
}

// ---------------- fused conv4d (implicit GEMM, 32x32x16 bf16 MFMA) -----------------
// Block 128 thr = 2 waves M-stacked. Wave tile M=128 (rr=4) x N=64 (nt=2).
// Block tile M=256 (v-span 8), N=64. Staging unit = one (kt,ku) stage x 32
// channels: LDS [10 rows][chunk4][wp34] 16B slots, padded to 1408/buffer;
// ping-pong. Pinned depth-1 pipeline (see header).
template <int CIN, int COUT, int NSPLIT, bool RELU>
__global__ __launch_bounds__(128, 2) void conv4d_mfma(
    const __bf16* __restrict__ in_t,   // chunk-planar activations
    const __bf16* __restrict__ wt,     // [81][CIN/16][COUT][16]
    const float* __restrict__ bias,    // [COUT]
    __bf16* __restrict__ out_bf,       // chunk-planar (RELU path)
    float* __restrict__ out_f,         // [2][COUT][65536]  (else)
    const __bf16* __restrict__ zpage)  // 4KB of zeros
{
    constexpr int KST     = CIN / 16;
    constexpr int UNITS   = CIN / 32;
    constexpr int LOGU    = (UNITS == 2) ? 1 : 2;
    constexpr int SLOTS   = 10 * 136;              // 1360 valid 16B slots
    constexpr int SLOTS_P = 1408;                  // padded to 11*128
    constexpr int RNDS    = 11;                    // DMA rounds (128 thr each)
    constexpr int BUFB_P  = SLOTS_P * 16;          // 22528 B

    __shared__ __bf16 tile[2 * SLOTS_P * 8];       // ping-pong, 45056 B

    const int tid  = threadIdx.x;                  // 0..127
    const int lane = tid & 63;
    const int l31  = lane & 31;
    const int hl   = lane >> 5;
    const int wv   = tid >> 6;                     // 0..1 = M-half

    // grid: bid = xcd(3) | s0;  s0 = ulo(0) | vg(1:2) | nb(3) | [nsp(4)] | t(hi 2)
    // t in the high bits -> co-resident blocks (bid +- 256) differ in t,
    // averaging the per-(t,u) stage-count imbalance on each CU.
    const int bid = blockIdx.x;
    const int xcd = bid & 7;
    const int s0  = bid >> 3;
    const int u   = xcd * 2 + (s0 & 1);
    const int vg  = (s0 >> 1) & 3;
    const int nb  = (s0 >> 3) & 1;
    const int nsp = (NSPLIT == 2) ? ((s0 >> 4) & 1) : 0;
    const int t   = (s0 >> ((NSPLIT == 2) ? 5 : 4)) & 3;
    const int v0  = vg * 8;
    const int pbase = ((t * 16 + u) * 32 + v0) * 32;

    const __bf16* inb = in_t + (size_t)nb * 65536 * CIN;

    // ---- per-lane staging offsets (slot = r*128 + tid), chunk-planar global ----
    int goff[RNDS];
    #pragma unroll
    for (int r = 0; r < RNDS; ++r) {
        const int slot = r * 128 + tid;            // 16B-chunk slot
        const int row  = slot / 136;               // LDS [10][chunk4][wp34]
        const int rem  = slot - row * 136;
        const int chunk = rem / 34;
        const int wp   = rem - chunk * 34;
        const int v_in = v0 - 1 + row;
        const int w_in = wp - 1;
        const bool ok = (slot < SLOTS) && ((unsigned)v_in < 32u) &&
                        ((unsigned)w_in < 32u);
        goff[r] = ok ? (v_in * (CIN * 32) + chunk * 256 + w_in * 8) : -1;
    }

    // A-read lane base: wave wv owns rows wv*4 .. wv*4+5 (incl. kv halo)
    const int lane_base = wv * 4 * 136 + hl * 34 + l31;
    const bf16x8* tile16 = (const bf16x8*)tile;

    // B lane pointer: o = nsp*64 + nt*32 + l31 (wave-independent: L1 dedup)
    const int o0 = nsp * 64 + l31;
    const __bf16* wlane = wt + (size_t)o0 * 16 + hl * 8;

    // ---- valid (kt,ku) stage list (block-uniform) ----
    int sb[9], tb0[9], nst = 0;
    #pragma unroll
    for (int kt = 0; kt < 3; ++kt) {
        const int t_in = t + kt - 1;
        if ((unsigned)t_in >= 4u) continue;
        #pragma unroll
        for (int ku = 0; ku < 3; ++ku) {
            const int u_in = u + ku - 1;
            if ((unsigned)u_in >= 16u) continue;
            sb[nst]  = (t_in * 16 + u_in) * 1024 * CIN;
            tb0[nst] = (kt * 3 + ku) * 9;
            ++nst;
        }
    }
    const int U = nst * UNITS;

    f32x16 acc[4][2];
    #pragma unroll
    for (int mt = 0; mt < 4; ++mt)
        #pragma unroll
        for (int nt = 0; nt < 2; ++nt)
            #pragma unroll
            for (int i = 0; i < 16; ++i)
                acc[mt][nt][i] = 0.f;

    // DMA issue for unit j into buffer `buf` (UNCONDITIONAL: 11 insts/wave;
    // halo/pad lanes read the zero page)
    auto issue = [&](int buf, int j) {
        const int st = j >> LOGU, ch = j & (UNITS - 1);
        const __bf16* gb = inb + sb[st] + ch * 1024;   // unit = 4 chunk-planes
        char* lb = ((char*)tile) + buf * BUFB_P + wv * 1024;
        #pragma unroll
        for (int r = 0; r < RNDS; ++r) {
            const __bf16* ga = (goff[r] >= 0) ? gb + goff[r] : zpage;
            gload_lds16(ga, lb + r * 2048);
        }
    };

    // A-fragment group load (6x ds_read_b128); g = (ks*3 + kw)
    auto ldA = [&](const bf16x8* tb, int g, bf16x8 (&af)[6]) {
        const int ks = g / 3, kw = g % 3;
        #pragma unroll
        for (int j = 0; j < 6; ++j)
            af[j] = tb[j * 136 + ks * 68 + kw];
    };
    // B-fragment group load (6x global 16B: 3 kv x 2 nt)
    auto ldB6 = [&](int tapb, int ch, int g, bf16x8 (&bv)[6]) {
        const int ks = g / 3, kw = g % 3;
        const int ksg = ch * 2 + ks;
        #pragma unroll
        for (int kv = 0; kv < 3; ++kv) {
            const int wo = ((tapb + kv * 3 + kw) * KST + ksg) * (COUT * 16);
            #pragma unroll
            for (int nt = 0; nt < 2; ++nt)
                bv[kv * 2 + nt] = *(const bf16x8*)(wlane + wo + nt * 512);
        }
    };
    // one (ks,kw) group's 24-MFMA cluster (3 kv x 2 nt x 4 rr)
    auto mfma24 = [&](bf16x8 (&af)[6], bf16x8 (&bv)[6]) {
        #pragma unroll
        for (int kv = 0; kv < 3; ++kv)
            #pragma unroll
            for (int nt = 0; nt < 2; ++nt)
                #pragma unroll
                for (int rr = 0; rr < 4; ++rr)
                    acc[rr][nt] = __builtin_amdgcn_mfma_f32_32x32x16_bf16(
                        af[rr + kv], bv[kv * 2 + nt], acc[rr][nt], 0, 0, 0);
    };

    issue(0, 0);

    #pragma unroll 1
    for (int i = 0; i < U; ++i) {
        // own-wave DMA(i) drain, then block-wide barrier (other wave's DMA
        // drained by its own vmcnt(0) before ITS barrier).
        asm volatile("s_waitcnt vmcnt(0)" ::: "memory");
        __builtin_amdgcn_s_barrier();
        SBAR();

        const int st = i >> LOGU, ch = i & (UNITS - 1);
        const int tapb = tb0[st];
        const bf16x8* tb = tile16 + (i & 1) * SLOTS_P + lane_base;

        bf16x8 afA[6], afB[6], bvA[6], bvB[6];
        // groups g=(ks,kw): g0..g5. Depth-1 pinned pipeline: loads for g+1
        // (or g+2) issued before cluster g; sched_barrier(0) fences prevent
        // the compiler sinking loads into their consuming cluster.
        ldB6(tapb, ch, 0, bvA); ldB6(tapb, ch, 1, bvB);
        ldA(tb, 0, afA); ldA(tb, 1, afB);
        SBAR();
        mfma24(afA, bvA); SBAR();
        ldA(tb, 2, afA); ldB6(tapb, ch, 2, bvA); SBAR();
        mfma24(afB, bvB); SBAR();
        ldA(tb, 3, afB); ldB6(tapb, ch, 3, bvB); SBAR();
        mfma24(afA, bvA); SBAR();
        ldA(tb, 4, afA); ldB6(tapb, ch, 4, bvA); SBAR();
        mfma24(afB, bvB); SBAR();
        ldA(tb, 5, afB); ldB6(tapb, ch, 5, bvB);
        // DMA(i+1) after ALL B loads of this iteration: every B-consumer
        // wait leaves it in flight; cover = 2 clusters + next-iter top.
        if (i + 1 < U) issue((i + 1) & 1, i + 1);
        SBAR();
        mfma24(afA, bvA); SBAR();
        mfma24(afB, bvB);
    }

    // ---- epilogue: C/D 32x32: col = lane&31, row = (reg&3) + 8*(reg>>2) + 4*hl ----
    #pragma unroll
    for (int nt = 0; nt < 2; ++nt) {
        const int o = o0 + nt * 32;
        const float bvls = bias[o];
        #pragma unroll
        for (int rr = 0; rr < 4; ++rr) {
            const int pb = pbase + (wv * 4 + rr) * 32;
            if constexpr (RELU) {
                #pragma unroll
                for (int rg = 0; rg < 4; ++rg)
                    #pragma unroll
                    for (int j = 0; j < 4; ++j) {
                        float v = acc[rr][nt][rg * 4 + j] + bvls;
                        v = v > 0.f ? v : 0.f;
                        const int p = pb + j + 8 * rg + 4 * hl;
                        const int vv = (p >> 5) & 31, ww = p & 31, tu = p >> 10;
                        out_bf[(size_t)nb * 65536 * COUT +
                               (size_t)(tu * 32 + vv) * (32 * COUT) +
                               (o >> 3) * 256 + ww * 8 + (o & 7)] = (__bf16)v;
                    }
            } else {
                #pragma unroll
                for (int rg = 0; rg < 4; ++rg) {
                    f32x4 sv;
                    #pragma unroll
                    for (int j = 0; j < 4; ++j)
                        sv[j] = acc[rr][nt][rg * 4 + j] + bvls;
                    const int p = pb + 8 * rg + 4 * hl;
                    *(f32x4*)(out_f + ((size_t)nb * COUT + o) * 65536 + p) = sv;
                }
            }
        }
    }
}

extern "C" void kernel_launch(void* const* d_in, const int* in_sizes, int n_in,
                              void* d_out, int out_size, void* d_ws, size_t ws_size,
                              hipStream_t stream) {
    const float* x  = (const float*)d_in[0];
    const float* w1 = (const float*)d_in[1];
    const float* b1 = (const float*)d_in[2];
    const float* w2 = (const float*)d_in[3];
    const float* b2 = (const float*)d_in[4];
    float* out = (float*)d_out;

    char* ws = (char*)d_ws;
    __bf16* x_t = (__bf16*)ws;                               // 16,777,216 B
    __bf16* h_t = (__bf16*)(ws + 16777216);                  // 33,554,432 B
    __bf16* w1t = (__bf16*)(ws + 50331648);                  //  1,327,104 B
    __bf16* w2t = (__bf16*)(ws + 51658752);                  //  1,327,104 B
    __bf16* zpg = (__bf16*)(ws + 52985856);                  //      4,096 B

    cvt_x<<<dim3(1024, 2), 256, 0, stream>>>(x, x_t, zpg);
    cvt_w<64><<<81, 256, 0, stream>>>(w1, w1t);
    cvt_w<128><<<81, 256, 0, stream>>>(w2, w2t);

    // conv1: block M=256 N=64, COUT split 2 -> grid 1024 (3/CU LDS-capped)
    conv4d_mfma<64, 128, 2, true><<<1024, 128, 0, stream>>>(x_t, w1t, b1, h_t,
                                                            nullptr, zpg);
    // conv2: block M=256 N=64 -> grid 512 (2/CU)
    conv4d_mfma<128, 64, 1, false><<<512, 128, 0, stream>>>(h_t, w2t, b2,
                                                            nullptr, out, zpg);
}

// Round 7
// 389.459 us; speedup vs baseline: 1.1330x; 1.1330x over previous
//
#include <hip/hip_runtime.h>

// ConvMlp4d: conv4d(64->128) + bias + relu -> conv4d(128->64) + bias.
// R17 = R16 + loop-exit drain/keep-alive (R16 crashed: dead dummy-load
// dest regs reused by epilogue, clobbered at load-retire -> GPU fault).
//   Diagnosis (R12/R14, VGPR=96): compiler JIT-sinks all B loads to just
//   before their consuming MFMA cluster; streaming A-traffic evicts
//   weights from L2 -> each cluster eats a ~700cy L3 miss serially ->
//   per-wave duty ~27%, MfmaUtil ~40 invariant.
//   Fix: B loads are asm volatile global_load_dwordx4 (cannot be sunk);
//   correctness depends only on exact counted waits, not scheduling:
//     top:  vmcnt(0)  -- DMA(i), firstB(i) ready (>=3-cluster cover)
//     mid:  vmcnt(16) -- retires exactly secB(i) (9 oldest of 25);
//                        DMA(i+1)[7] + firstB(i+1)[9] stay in flight
//     exit: vmcnt(0) + keep-alive of all asm-load dests (liveness must
//           span the drain, else regalloc reuse -> retire-time clobber)
//   Issue order/iter: [secB(i) 9][DMA(i+1) 7][g0-2][firstB(i+1) 9]
//                     [vmcnt(16)][g3-5]; sparse SBAR fences at segment
//   boundaries only. Rule#18: every waitcnt asm followed by SBAR.
//   Geometry (R12): 128-thr blocks, 2 waves N-split, wave tile M=128(rr=4)
//   x N=32, VSPAN=4 ROWS=6, LDS 28672 (5 blocks/CU); conv1 grid 2048
//   (COUT split 2), conv2 grid 1024.
//   ws: x_t bf16 [2][65536][64] | h_t bf16 [2][65536][128] (chunk-planar:
//       [nb][tu][v][chunk=c/8][w][c%8])
//       w1t bf16 [81][4][128][16] | w2t bf16 [81][8][64][16] | zpage 4KB

using bf16x8 = __attribute__((ext_vector_type(8))) __bf16;
using f32x16 = __attribute__((ext_vector_type(16))) float;
using f32x4  = __attribute__((ext_vector_type(4))) float;

typedef __attribute__((address_space(1))) const void as1_void;
typedef __attribute__((address_space(3))) void as3_void;
__device__ __forceinline__ void gload_lds16(const void* g, void* l) {
    __builtin_amdgcn_global_load_lds((as1_void*)g, (as3_void*)l, 16, 0, 0);
}
// pinned 16B global load: volatile asm -> compiler cannot sink it into the
// consuming cluster. No waitcnt contract: consumers rely on the explicit
// counted waits in the main loop; dests must stay live past a drain.
__device__ __forceinline__ bf16x8 gload16(const __bf16* p) {
    bf16x8 r;
    asm volatile("global_load_dwordx4 %0, %1, off" : "=v"(r) : "v"(p));
    return r;
}
#define SBAR() __builtin_amdgcn_sched_barrier(0)

// ------- prep: x (2,64,65536) f32 -> x_t chunk-planar bf16; zero the zpage --------
__global__ __launch_bounds__(256) void cvt_x(const float* __restrict__ x,
                                             __bf16* __restrict__ x_t,
                                             __bf16* __restrict__ zp) {
    __shared__ float lt[64][65];
    if (blockIdx.x == 0 && blockIdx.y == 0)
        *(uint4*)((char*)zp + threadIdx.x * 16) = make_uint4(0u, 0u, 0u, 0u);
    const int nb = blockIdx.y;
    const int p0 = blockIdx.x * 64;
    const int tu = p0 >> 10;
    const float* src = x + (size_t)nb * 64 * 65536;
    __bf16* dst = x_t + (size_t)nb * 65536 * 64;
    #pragma unroll
    for (int i = 0; i < 16; ++i) {
        int idx = i * 256 + threadIdx.x;
        int c = idx >> 6, p = idx & 63;
        lt[c][p] = src[(size_t)c * 65536 + p0 + p];
    }
    __syncthreads();
    #pragma unroll
    for (int it = 0; it < 2; ++it) {
        int idx = it * 256 + threadIdx.x;
        int pl = idx & 63;
        int chunk = idx >> 6;
        int p = p0 + pl;
        int v = (p >> 5) & 31, w = p & 31;
        bf16x8 pk;
        #pragma unroll
        for (int e = 0; e < 8; ++e)
            pk[e] = (__bf16)lt[chunk * 8 + e][pl];
        *(bf16x8*)(dst + (size_t)(tu * 32 + v) * 2048 + chunk * 256 + w * 8) = pk;
    }
}

// ------- prep: w (O,CIN,81) f32 -> wt [81][CIN/16][COUT][16] bf16 ------------------
template <int CIN>
__global__ __launch_bounds__(256) void cvt_w(const float* __restrict__ w,
                                             __bf16* __restrict__ wt) {
    constexpr int COUT = 8192 / CIN;
    constexpr int LOGC = (CIN == 64) ? 7 : 6;   // log2(COUT)
    const int tap = blockIdx.x;                 // 0..80
    __bf16* dst = wt + (size_t)tap * 8192;
    #pragma unroll
    for (int it = 0; it < 32; ++it) {
        const int i  = it * 256 + threadIdx.x;  // kg*(COUT*16) + o*16 + cl
        const int cl = i & 15;
        const int o  = (i >> 4) & (COUT - 1);
        const int kg = i >> (4 + LOGC);
        dst[i] = (__bf16)w[(size_t)(o * CIN + kg * 16 + cl) * 81 + tap];
    }
}

// ---------------- fused conv4d (implicit GEMM, 32x32x16 bf16 MFMA) -----------------
// Block 128 thr = 2 waves (gni = wave). Wave tile M=128 (rr=4), N=32.
// Block tile M=128 (v-span 4), N=64; conv1 splits COUT 128 into 2 n-blocks.
// Staging unit = one (kt,ku) stage x 32 channels: LDS [6 rows][chunk4][wp34] 16B
// slots, padded to 896/buffer; ping-pong.
template <int CIN, int COUT, int NSPLIT, bool RELU>
__global__ __launch_bounds__(128, 2) void conv4d_mfma(
    const __bf16* __restrict__ in_t,   // chunk-planar activations
    const __bf16* __restrict__ wt,     // [81][CIN/16][COUT][16]
    const float* __restrict__ bias,    // [COUT]
    __bf16* __restrict__ out_bf,       // chunk-planar (RELU path)
    float* __restrict__ out_f,         // [2][COUT][65536]  (else)
    const __bf16* __restrict__ zpage)  // 4KB of zeros
{
    constexpr int KST     = CIN / 16;
    constexpr int UNITS   = CIN / 32;
    constexpr int LOGU    = (UNITS == 2) ? 1 : 2;
    constexpr int SLOTS   = 6 * 136;               // 816 valid 16B slots
    constexpr int SLOTS_P = 896;                   // padded to 7*128
    constexpr int RNDS    = 7;                     // DMA rounds (128 thr each)
    constexpr int BUFB_P  = SLOTS_P * 16;          // 14336 B

    __shared__ __bf16 tile[2 * SLOTS_P * 8];       // ping-pong, 28672 B

    const int tid  = threadIdx.x;                  // 0..127
    const int lane = tid & 63;
    const int l31  = lane & 31;
    const int hl   = lane >> 5;
    const int wv   = tid >> 6;                     // 0..1 = gni

    // grid: xcd(3) | ulo(1) | vg(3) | t(2) | nb(1) | nsp(log2 NSPLIT)
    const int bid = blockIdx.x;
    const int xcd = bid & 7;
    const int s0  = bid >> 3;
    const int u   = xcd * 2 + (s0 & 1);
    const int vg  = (s0 >> 1) & 7;
    const int t   = (s0 >> 4) & 3;
    const int nb  = (s0 >> 6) & 1;
    const int nsp = (s0 >> 7) & (NSPLIT - 1);
    const int v0  = vg * 4;
    const int pbase = ((t * 16 + u) * 32 + v0) * 32;

    const __bf16* inb = in_t + (size_t)nb * 65536 * CIN;

    // ---- per-lane staging offsets (slot = r*128 + tid), chunk-planar global ----
    int goff[RNDS];
    #pragma unroll
    for (int r = 0; r < RNDS; ++r) {
        const int slot = r * 128 + tid;            // 16B-chunk slot
        const int row  = slot / 136;               // LDS [6][chunk4][wp34]
        const int rem  = slot - row * 136;
        const int chunk = rem / 34;
        const int wp   = rem - chunk * 34;
        const int v_in = v0 - 1 + row;
        const int w_in = wp - 1;
        const bool ok = (slot < SLOTS) && ((unsigned)v_in < 32u) &&
                        ((unsigned)w_in < 32u);
        goff[r] = ok ? (v_in * (CIN * 32) + chunk * 256 + w_in * 8) : -1;
    }

    // A-read lane base (16B slots): slot = j*136 + (ks*2+hl)*34 + l31 + kw
    const int lane_base = hl * 34 + l31;
    const bf16x8* tile16 = (const bf16x8*)tile;

    // B lane pointer: o = nsp*64 + gni*32 + l31; + hl*8 within the 16-ch group
    const int o = nsp * 64 + wv * 32 + l31;
    const __bf16* wlane = wt + (size_t)o * 16 + hl * 8;

    // ---- valid (kt,ku) stage list (block-uniform) ----
    int sb[9], tb0[9], nst = 0;
    #pragma unroll
    for (int kt = 0; kt < 3; ++kt) {
        const int t_in = t + kt - 1;
        if ((unsigned)t_in >= 4u) continue;
        #pragma unroll
        for (int ku = 0; ku < 3; ++ku) {
            const int u_in = u + ku - 1;
            if ((unsigned)u_in >= 16u) continue;
            sb[nst]  = (t_in * 16 + u_in) * 1024 * CIN;
            tb0[nst] = (kt * 3 + ku) * 9;
            ++nst;
        }
    }
    const int U = nst * UNITS;

    f32x16 acc[4];
    #pragma unroll
    for (int mt = 0; mt < 4; ++mt)
        #pragma unroll
        for (int i = 0; i < 16; ++i)
            acc[mt][i] = 0.f;

    // DMA issue for unit j into buffer `buf` (UNCONDITIONAL: 7 insts/wave;
    // halo/pad lanes read the zero page)
    auto issue = [&](int buf, int j) {
        const int st = j >> LOGU, ch = j & (UNITS - 1);
        const __bf16* gb = inb + sb[st] + ch * 1024;   // unit = 4 chunk-planes
        char* lb = ((char*)tile) + buf * BUFB_P + wv * 1024;
        #pragma unroll
        for (int r = 0; r < RNDS; ++r) {
            const __bf16* ga = (goff[r] >= 0) ? gb + goff[r] : zpage;
            gload_lds16(ga, lb + r * 2048);
        }
    };

    // A-fragment group load (6x ds_read_b128); g = (ks*3 + kw)
    auto ldA = [&](const bf16x8* tb, int g, bf16x8 (&af)[6]) {
        const int ks = g / 3, kw = g % 3;
        #pragma unroll
        for (int j = 0; j < 6; ++j)
            af[j] = tb[j * 136 + ks * 68 + kw];
    };
    // pinned B-fragment group load (3x asm global 16B) into dst[0..2]
    auto ldB3 = [&](int tapb, int ch, int g, bf16x8* dst) {
        const int ks = g / 3, kw = g % 3;
        const int ksg = ch * 2 + ks;
        #pragma unroll
        for (int kv = 0; kv < 3; ++kv) {
            const int wo = ((tapb + kv * 3 + kw) * KST + ksg) * (COUT * 16);
            dst[kv] = gload16(wlane + wo);
        }
    };
    // one (ks,kw) group's 12-MFMA cluster
    auto mfma12 = [&](bf16x8 (&af)[6], const bf16x8& b0, const bf16x8& b1,
                      const bf16x8& b2) {
        #pragma unroll
        for (int rr = 0; rr < 4; ++rr)
            acc[rr] = __builtin_amdgcn_mfma_f32_32x32x16_bf16(af[rr + 0], b0,
                                                              acc[rr], 0, 0, 0);
        #pragma unroll
        for (int rr = 0; rr < 4; ++rr)
            acc[rr] = __builtin_amdgcn_mfma_f32_32x32x16_bf16(af[rr + 1], b1,
                                                              acc[rr], 0, 0, 0);
        #pragma unroll
        for (int rr = 0; rr < 4; ++rr)
            acc[rr] = __builtin_amdgcn_mfma_f32_32x32x16_bf16(af[rr + 2], b2,
                                                              acc[rr], 0, 0, 0);
    };

    // ---- prologue: DMA(0) then firstB(0) ----
    issue(0, 0);
    bf16x8 bvF[9], bvS[9];
    #pragma unroll
    for (int g = 0; g < 3; ++g)
        ldB3(tb0[0], 0, g, &bvF[g * 3]);

    #pragma unroll 1
    for (int i = 0; i < U; ++i) {
        // Everything outstanding (DMA(i), firstB(i)) had >=3 clusters of
        // cover. Single full drain; barrier publishes the LDS tile.
        asm volatile("s_waitcnt vmcnt(0)" ::: "memory");
        __builtin_amdgcn_s_barrier();
        SBAR();                                   // rule#18 fence

        const int st = i >> LOGU, ch = i & (UNITS - 1);
        const int tapb = tb0[st];
        const bool more = (i + 1 < U);
        const int nu = more ? i + 1 : i;          // last iter: dummy
        const int ntapb = tb0[nu >> LOGU];
        const int nch   = nu & (UNITS - 1);
        const bf16x8* tb = tile16 + (i & 1) * SLOTS_P + lane_base;

        // secB(i): groups g3..g5 (the 9 OLDEST vmem ops of this iter)
        #pragma unroll
        for (int g = 0; g < 3; ++g)
            ldB3(tapb, ch, g + 3, &bvS[g * 3]);
        SBAR();
        issue((i + 1) & 1, nu);                   // DMA(i+1): 7 loads
        SBAR();

        bf16x8 af[6];
        ldA(tb, 0, af); mfma12(af, bvF[0], bvF[1], bvF[2]);
        ldA(tb, 1, af); mfma12(af, bvF[3], bvF[4], bvF[5]);
        ldA(tb, 2, af); mfma12(af, bvF[6], bvF[7], bvF[8]);
        // firstB(i+1): overwrites bvF (WAR after last bvF consume above)
        #pragma unroll
        for (int g = 0; g < 3; ++g)
            ldB3(ntapb, nch, g, &bvF[g * 3]);
        SBAR();
        // retire exactly secB(i): 25 outstanding, secB are the 9 oldest.
        asm volatile("s_waitcnt vmcnt(16)" ::: "memory");
        SBAR();                                   // rule#18 fence
        ldA(tb, 3, af); mfma12(af, bvS[0], bvS[1], bvS[2]);
        ldA(tb, 4, af); mfma12(af, bvS[3], bvS[4], bvS[5]);
        ldA(tb, 5, af); mfma12(af, bvS[6], bvS[7], bvS[8]);
    }

    // ---- loop-exit drain: last iteration's dummy DMA + firstB are still in
    // flight; their dest regs MUST stay live past this drain or regalloc
    // reuses them and the retiring loads clobber epilogue values (R16 fault).
    asm volatile("s_waitcnt vmcnt(0)" ::: "memory");
    SBAR();
    asm volatile("" ::
        "v"(bvF[0]), "v"(bvF[1]), "v"(bvF[2]), "v"(bvF[3]), "v"(bvF[4]),
        "v"(bvF[5]), "v"(bvF[6]), "v"(bvF[7]), "v"(bvF[8]));
    SBAR();

    // ---- epilogue: C/D 32x32: col = lane&31, row = (reg&3) + 8*(reg>>2) + 4*hl ----
    {
        const float bvls = bias[o];
        #pragma unroll
        for (int rr = 0; rr < 4; ++rr) {
            const int pb = pbase + rr * 32;
            if constexpr (RELU) {
                #pragma unroll
                for (int rg = 0; rg < 4; ++rg)
                    #pragma unroll
                    for (int j = 0; j < 4; ++j) {
                        float v = acc[rr][rg * 4 + j] + bvls;
                        v = v > 0.f ? v : 0.f;
                        const int p = pb + j + 8 * rg + 4 * hl;
                        const int vv = (p >> 5) & 31, ww = p & 31, tu = p >> 10;
                        out_bf[(size_t)nb * 65536 * COUT +
                               (size_t)(tu * 32 + vv) * (32 * COUT) +
                               (o >> 3) * 256 + ww * 8 + (o & 7)] = (__bf16)v;
                    }
            } else {
                #pragma unroll
                for (int rg = 0; rg < 4; ++rg) {
                    f32x4 sv;
                    #pragma unroll
                    for (int j = 0; j < 4; ++j)
                        sv[j] = acc[rr][rg * 4 + j] + bvls;
                    const int p = pb + 8 * rg + 4 * hl;
                    *(f32x4*)(out_f + ((size_t)nb * COUT + o) * 65536 + p) = sv;
                }
            }
        }
    }
}

extern "C" void kernel_launch(void* const* d_in, const int* in_sizes, int n_in,
                              void* d_out, int out_size, void* d_ws, size_t ws_size,
                              hipStream_t stream) {
    const float* x  = (const float*)d_in[0];
    const float* w1 = (const float*)d_in[1];
    const float* b1 = (const float*)d_in[2];
    const float* w2 = (const float*)d_in[3];
    const float* b2 = (const float*)d_in[4];
    float* out = (float*)d_out;

    char* ws = (char*)d_ws;
    __bf16* x_t = (__bf16*)ws;                               // 16,777,216 B
    __bf16* h_t = (__bf16*)(ws + 16777216);                  // 33,554,432 B
    __bf16* w1t = (__bf16*)(ws + 50331648);                  //  1,327,104 B
    __bf16* w2t = (__bf16*)(ws + 51658752);                  //  1,327,104 B
    __bf16* zpg = (__bf16*)(ws + 52985856);                  //      4,096 B

    cvt_x<<<dim3(1024, 2), 256, 0, stream>>>(x, x_t, zpg);
    cvt_w<64><<<81, 256, 0, stream>>>(w1, w1t);
    cvt_w<128><<<81, 256, 0, stream>>>(w2, w2t);

    // conv1: 128-thr blocks, M=128 N=64, COUT split 2 -> grid 2048
    conv4d_mfma<64, 128, 2, true><<<2048, 128, 0, stream>>>(x_t, w1t, b1, h_t,
                                                            nullptr, zpg);
    // conv2: 128-thr blocks, M=128 N=64, grid 1024 (5 blocks/CU LDS-capped)
    conv4d_mfma<128, 64, 1, false><<<1024, 128, 0, stream>>>(h_t, w2t, b2,
                                                             nullptr, out, zpg);
}